// Round 9
// baseline (305.912 us; speedup 1.0000x reference)
//
#include <hip/hip_runtime.h>
#include <hip/hip_bf16.h>

#define IN_F   4096
#define OUT_F  4096
#define M_ROWS 8192
#define RANK   16
#define SCALING 2.0f

#define BM 256
#define BN 256
#define BK 64
#define NT (IN_F / BK)   // 64 K-tiles

typedef __attribute__((ext_vector_type(8))) short bf16x8;
typedef __attribute__((ext_vector_type(4))) float f32x4;
typedef unsigned short ushort_t;

template<int V> struct ic { static constexpr int value = V; };

__device__ __forceinline__ short f2b(float f) {
    union { float f; unsigned u; } c; c.f = f;
    unsigned r = (c.u + 0x7FFFu + ((c.u >> 16) & 1u)) >> 16;
    return (short)r;
}

__device__ __forceinline__ float4 ld4(const float* p) { return *(const float4*)p; }

__device__ __forceinline__ float4 s4(float4 v, float s) {
    v.x *= s; v.y *= s; v.z *= s; v.w *= s; return v;
}

__device__ __forceinline__ bf16x8 pack8(float4 a, float4 b) {
    bf16x8 r;
    r[0] = f2b(a.x); r[1] = f2b(a.y); r[2] = f2b(a.z); r[3] = f2b(a.w);
    r[4] = f2b(b.x); r[5] = f2b(b.y); r[6] = f2b(b.z); r[7] = f2b(b.w);
    return r;
}

__device__ __forceinline__ void gload16(const void* g, void* l) {
    __builtin_amdgcn_global_load_lds(
        (const __attribute__((address_space(1))) unsigned int*)g,
        (__attribute__((address_space(3))) unsigned int*)l, 16, 0, 0);
}

#define FENCE() asm volatile("" ::: "memory")

// ======== prep: convert x,W to bf16 + compute T = x@A^T, one dispatch (r8-proven) ========
__global__ __launch_bounds__(256) void prep_kernel(
        const float* __restrict__ x, const float* __restrict__ w,
        const float* __restrict__ lora_A,
        ushort_t* __restrict__ xb, ushort_t* __restrict__ wb,
        float* __restrict__ T) {
    const int tid = threadIdx.x;
    if (blockIdx.x < 512) {
        __shared__ float part[4][16][16];
        const int lane = tid & 63, wv = tid >> 6;   // 4 waves; wave = K-quarter
        const int l15 = lane & 15, lk = lane >> 4;
        const int r0 = blockIdx.x * 16;
        const int kq = wv * 1024;
        const float*  xr = x      + (size_t)(r0 + l15) * IN_F + kq + lk * 8;
        const float*  ar = lora_A + (size_t)l15        * IN_F + kq + lk * 8;
        ushort_t*     xw = xb     + (size_t)(r0 + l15) * IN_F + kq + lk * 8;
        f32x4 accT = (f32x4){0.f, 0.f, 0.f, 0.f};
#pragma unroll 4
        for (int it = 0; it < 1024; it += 32) {
            bf16x8 xf = pack8(ld4(xr + it), ld4(xr + it + 4));
            *(bf16x8*)(xw + it) = xf;
            bf16x8 afr = pack8(ld4(ar + it), ld4(ar + it + 4));
            accT = __builtin_amdgcn_mfma_f32_16x16x32_bf16(xf, afr, accT, 0, 0, 0);
        }
#pragma unroll
        for (int v = 0; v < 4; v++) part[wv][lk * 4 + v][l15] = accT[v];
        __syncthreads();
        if (tid < 64) {
#pragma unroll
            for (int e = 0; e < 4; e++) {
                const int idx = tid * 4 + e;
                const int i = idx >> 4, j = idx & 15;
                T[(size_t)(r0 + i) * RANK + j] =
                    part[0][i][j] + part[1][i][j] + part[2][i][j] + part[3][i][j];
            }
        }
    } else {
        const int n8w = OUT_F * IN_F / 8;
        int i = (blockIdx.x - 512) * 256 + tid;
        const int stride = 1024 * 256;
        for (; i < n8w; i += stride) {
            const float* p = w + (size_t)i * 8;
            *(bf16x8*)(wb + (size_t)i * 8) = pack8(ld4(p), ld4(p + 4));
        }
    }
}

// ====== main GEMM: 256x256, BK=64, 8-wave, 1 barrier/phase, depth-3 stage map, vmcnt(6) ======
__global__ __launch_bounds__(512, 1) void gemm8p(
        const ushort_t* __restrict__ xb, const ushort_t* __restrict__ wb,
        const float* __restrict__ bias, const float* __restrict__ lora_B,
        const float* __restrict__ T, float* __restrict__ out) {

    __shared__ __align__(16) ushort_t As[2][BM * BK];   // 64 KiB
    __shared__ __align__(16) ushort_t Bs[2][BN * BK];   // 64 KiB

    const int tid  = threadIdx.x;
    const int lane = tid & 63, wv = tid >> 6;
    const int wm = wv >> 2, wn = wv & 3;          // 2 x 4 wave grid; wave tile 128x64
    const int l15 = lane & 15, lk = lane >> 4;

    // XCD-aware block swizzle (row-band: each XCD gets 4 by-panels x all bx)
    const int bid = blockIdx.x;
    const int swz = (bid & 7) * 64 + (bid >> 3);
    const int by = swz >> 4, bx = swz & 15;       // 32 x 16 tile grid
    const int brow = by * BM, bcol = bx * BN;

    // ---- staging coords ----
    const int off0 = wv * 2048 + lane * 16;
    const int off1 = off0 + 1024;
    const int row0 = off0 >> 7, row1 = off1 >> 7;
    const int sc0 = ((off0 & 127) ^ ((row0 & 7) << 4)) >> 1;  // pre-swizzled src elem col
    const int sc1 = ((off1 & 127) ^ ((row1 & 7) << 4)) >> 1;
    const int ldst = wv * 1024;

    const size_t gA0 = (size_t)(brow + row0) * IN_F + sc0;
    const size_t gA1 = (size_t)(brow + row1) * IN_F + sc1;
    const size_t gB0 = (size_t)(bcol + row0) * IN_F + sc0;
    const size_t gB1 = (size_t)(bcol + row1) * IN_F + sc1;

    auto SA = [&](int h, int kt, auto BB) {
        constexpr int b = decltype(BB)::value;
        const size_t ho = (size_t)h * (128 * IN_F);
        gload16(xb + gA0 + ho + kt * 64, &As[b][h * 8192 + ldst]);
        gload16(xb + gA1 + ho + kt * 64, &As[b][h * 8192 + ldst + 512]);
    };
    auto SB = [&](int h, int kt, auto BB) {
        constexpr int b = decltype(BB)::value;
        const size_t ho = (size_t)h * (128 * IN_F);
        gload16(wb + gB0 + ho + kt * 64, &Bs[b][h * 8192 + ldst]);
        gload16(wb + gB1 + ho + kt * 64, &Bs[b][h * 8192 + ldst + 512]);
    };

    const int cb0 = (lk * 16) ^ ((l15 & 7) << 4);
    const int cb1 = (64 + lk * 16) ^ ((l15 & 7) << 4);
    const int am = wm * 128, bn = wn * 64;

    f32x4 acc[8][4];
#pragma unroll
    for (int m = 0; m < 8; m++)
#pragma unroll
        for (int n = 0; n < 4; n++) acc[m][n] = (f32x4){0.f, 0.f, 0.f, 0.f};

    bf16x8 af[8], bfq[8];

    // ---- prologue: tile0 full (buf0, 8 loads) + tile1 B0,B1,A0 (buf1, 6 loads) ----
    // A1(tile1) staged at iter-0 ph1. Gate: 14 issued, need first 8 -> vmcnt(6).
    SA(0, 0, ic<0>{}); SA(1, 0, ic<0>{});
    SB(0, 0, ic<0>{}); SB(1, 0, ic<0>{});
    SB(0, 1, ic<1>{}); SB(1, 1, ic<1>{}); SA(0, 1, ic<1>{});
    asm volatile("s_waitcnt vmcnt(6)" ::: "memory");
    __builtin_amdgcn_s_barrier();
    FENCE();

    // Depth-3 stage map, 1 barrier/phase.
    // ph1: read af-h0 + ALL bfq; stage A1(t+1)->n; MFMA (mh0,n01)
    // ph2: stage B0(t+2)->c;                       MFMA (mh0,n23)
    // ph3: read af-h1; stage B1(t+2)->c;           MFMA (mh1,n23)
    // ph4: stage A0(t+2)->c;                       MFMA (mh1,n01); vmcnt(6)
    // Race-safety: cur-B only read in ph1 (all bfq); cur-A0 last read ph3 (wm=0);
    // each stage target's readers passed >=1 phase-end barrier upstream.
    auto TB = [&](auto CC, int tt) {
        constexpr int c = decltype(CC)::value;
        constexpr int n = c ^ 1;
        const int kt1 = (tt + 1 < NT) ? tt + 1 : NT - 1;
        const int kt2 = (tt + 2 < NT) ? tt + 2 : NT - 1;

        // ---- phase 1 ----
#pragma unroll
        for (int mi = 0; mi < 4; mi++) {
            const char* rp = (const char*)&As[c][0] + (am + mi * 16 + l15) * 128;
            af[mi * 2]     = *(const bf16x8*)(rp + cb0);
            af[mi * 2 + 1] = *(const bf16x8*)(rp + cb1);
        }
#pragma unroll
        for (int ni = 0; ni < 4; ni++) {
            const char* rp = (const char*)&Bs[c][0] + (bn + ni * 16 + l15) * 128;
            bfq[ni * 2]     = *(const bf16x8*)(rp + cb0);
            bfq[ni * 2 + 1] = *(const bf16x8*)(rp + cb1);
        }
        SA(1, kt1, ic<n>{});
        __builtin_amdgcn_s_setprio(1);
#pragma unroll
        for (int mi = 0; mi < 4; mi++)
#pragma unroll
            for (int ni = 0; ni < 2; ni++)
#pragma unroll
                for (int ks = 0; ks < 2; ks++)
                    acc[mi][ni] = __builtin_amdgcn_mfma_f32_16x16x32_bf16(
                        af[mi * 2 + ks], bfq[ni * 2 + ks], acc[mi][ni], 0, 0, 0);
        __builtin_amdgcn_s_setprio(0);
        FENCE();
        __builtin_amdgcn_s_barrier();
        FENCE();

        // ---- phase 2 ----
        SB(0, kt2, ic<c>{});
        __builtin_amdgcn_s_setprio(1);
#pragma unroll
        for (int mi = 0; mi < 4; mi++)
#pragma unroll
            for (int ni = 0; ni < 2; ni++)
#pragma unroll
                for (int ks = 0; ks < 2; ks++)
                    acc[mi][2 + ni] = __builtin_amdgcn_mfma_f32_16x16x32_bf16(
                        af[mi * 2 + ks], bfq[(2 + ni) * 2 + ks], acc[mi][2 + ni], 0, 0, 0);
        __builtin_amdgcn_s_setprio(0);
        FENCE();
        __builtin_amdgcn_s_barrier();
        FENCE();

        // ---- phase 3 ----
#pragma unroll
        for (int mi = 0; mi < 4; mi++) {
            const char* rp = (const char*)&As[c][0] + (am + 64 + mi * 16 + l15) * 128;
            af[mi * 2]     = *(const bf16x8*)(rp + cb0);
            af[mi * 2 + 1] = *(const bf16x8*)(rp + cb1);
        }
        SB(1, kt2, ic<c>{});
        __builtin_amdgcn_s_setprio(1);
#pragma unroll
        for (int mi = 0; mi < 4; mi++)
#pragma unroll
            for (int ni = 0; ni < 2; ni++)
#pragma unroll
                for (int ks = 0; ks < 2; ks++)
                    acc[4 + mi][2 + ni] = __builtin_amdgcn_mfma_f32_16x16x32_bf16(
                        af[mi * 2 + ks], bfq[(2 + ni) * 2 + ks], acc[4 + mi][2 + ni], 0, 0, 0);
        __builtin_amdgcn_s_setprio(0);
        FENCE();
        __builtin_amdgcn_s_barrier();
        FENCE();

        // ---- phase 4 ----
        SA(0, kt2, ic<c>{});
        __builtin_amdgcn_s_setprio(1);
#pragma unroll
        for (int mi = 0; mi < 4; mi++)
#pragma unroll
            for (int ni = 0; ni < 2; ni++)
#pragma unroll
                for (int ks = 0; ks < 2; ks++)
                    acc[4 + mi][ni] = __builtin_amdgcn_mfma_f32_16x16x32_bf16(
                        af[mi * 2 + ks], bfq[ni * 2 + ks], acc[4 + mi][ni], 0, 0, 0);
        __builtin_amdgcn_s_setprio(0);
        asm volatile("s_waitcnt vmcnt(6)" ::: "memory");  // tile t+1 fully landed
        __builtin_amdgcn_s_barrier();
        FENCE();
    };

    for (int tt = 0; tt < NT; tt += 2) {
        TB(ic<0>{}, tt);
        TB(ic<1>{}, tt + 1);
    }

    // ---- LoRA rank-update: one K=32 MFMA step (linear LDS, reg-staged) ----
    asm volatile("s_waitcnt vmcnt(0)" ::: "memory");
    __builtin_amdgcn_s_barrier();
    {
        const int r = tid >> 1, hh = tid & 1;
        ushort_t* LA = &As[0][0];
        ushort_t* LB = &Bs[0][0];
        if (hh == 0) {
            const float* tp = T + (size_t)(brow + r) * RANK;
            *(bf16x8*)&LA[r * 32]     = pack8(s4(ld4(tp), SCALING), s4(ld4(tp + 4), SCALING));
            *(bf16x8*)&LA[r * 32 + 8] = pack8(s4(ld4(tp + 8), SCALING), s4(ld4(tp + 12), SCALING));
            const float* bp = lora_B + (size_t)(bcol + r) * RANK;
            *(bf16x8*)&LB[r * 32]     = pack8(ld4(bp), ld4(bp + 4));
            *(bf16x8*)&LB[r * 32 + 8] = pack8(ld4(bp + 8), ld4(bp + 12));
        } else {
            bf16x8 z;
#pragma unroll
            for (int i = 0; i < 8; i++) z[i] = 0;
            *(bf16x8*)&LA[r * 32 + 16] = z; *(bf16x8*)&LA[r * 32 + 24] = z;
            *(bf16x8*)&LB[r * 32 + 16] = z; *(bf16x8*)&LB[r * 32 + 24] = z;
        }
    }
    __syncthreads();
    {
        const ushort_t* LA = &As[0][0];
        const ushort_t* LB = &Bs[0][0];
        bf16x8 bfL[4];
#pragma unroll
        for (int n = 0; n < 4; n++)
            bfL[n] = *(const bf16x8*)&LB[(bn + n * 16 + l15) * 32 + lk * 8];
#pragma unroll
        for (int m = 0; m < 8; m++) {
            bf16x8 afL = *(const bf16x8*)&LA[(am + m * 16 + l15) * 32 + lk * 8];
#pragma unroll
            for (int n = 0; n < 4; n++)
                acc[m][n] = __builtin_amdgcn_mfma_f32_16x16x32_bf16(afL, bfL[n], acc[m][n], 0, 0, 0);
        }
    }

    // ---- epilogue: + bias, store ----
#pragma unroll
    for (int n = 0; n < 4; n++) {
        const int col = bcol + bn + n * 16 + l15;
        const float bv = bias[col];
#pragma unroll
        for (int m = 0; m < 8; m++) {
            const int row0_ = brow + am + m * 16 + lk * 4;
#pragma unroll
            for (int v = 0; v < 4; v++)
                out[(size_t)(row0_ + v) * OUT_F + col] = acc[m][n][v] + bv;
        }
    }
}

// ================= fp32 fallback path (small ws) =================
__global__ __launch_bounds__(256) void lora_t_kernel(const float* __restrict__ x,
                                                     const float* __restrict__ lora_A,
                                                     float* __restrict__ T) {
    const int t   = threadIdx.x;
    const int row = blockIdx.x * 16 + (t >> 4);
    const int rr  = t & 15;
    const float* xr = x + (size_t)row * IN_F;
    const float* ar = lora_A + (size_t)rr * IN_F;
    float acc = 0.f;
#pragma unroll 8
    for (int k = 0; k < IN_F; k += 4) {
        float4 xv = ld4(xr + k);
        float4 av = ld4(ar + k);
        acc += xv.x * av.x + xv.y * av.y + xv.z * av.z + xv.w * av.w;
    }
    T[row * RANK + rr] = acc;
}

__global__ __launch_bounds__(256) void lora_gemm_kernel(
        const float* __restrict__ x, const float* __restrict__ w,
        const float* __restrict__ bias, const float* __restrict__ lora_B,
        const float* __restrict__ T, float* __restrict__ out) {

    __shared__ __align__(16) short As[128][32];
    __shared__ __align__(16) short Bs[128][32];

    const int t    = threadIdx.x;
    const int brow = blockIdx.y * 128;
    const int bcol = blockIdx.x * 128;
    const int srow  = t >> 1;
    const int shalf = (t & 1) << 4;
    const float* xa = x + (size_t)(brow + srow) * IN_F + shalf;
    const float* wb = w + (size_t)(bcol + srow) * IN_F + shalf;
    const int lane = t & 63;
    const int wv   = t >> 6;
    const int wr   = wv >> 1, wc = wv & 1;
    const int l15  = lane & 15, lk = lane >> 4;

    f32x4 acc[4][4];
#pragma unroll
    for (int m = 0; m < 4; m++)
#pragma unroll
        for (int n = 0; n < 4; n++)
            acc[m][n] = (f32x4){0.f, 0.f, 0.f, 0.f};

    for (int k0 = 0; k0 < IN_F; k0 += 32) {
        float4 a0 = ld4(xa + k0);      float4 a1 = ld4(xa + k0 + 4);
        float4 a2 = ld4(xa + k0 + 8);  float4 a3 = ld4(xa + k0 + 12);
        float4 b0 = ld4(wb + k0);      float4 b1 = ld4(wb + k0 + 4);
        float4 b2 = ld4(wb + k0 + 8);  float4 b3 = ld4(wb + k0 + 12);

        __syncthreads();
        *(bf16x8*)&As[srow][shalf]     = pack8(a0, a1);
        *(bf16x8*)&As[srow][shalf + 8] = pack8(a2, a3);
        *(bf16x8*)&Bs[srow][shalf]     = pack8(b0, b1);
        *(bf16x8*)&Bs[srow][shalf + 8] = pack8(b2, b3);
        __syncthreads();

        bf16x8 af[4], bf[4];
#pragma unroll
        for (int m = 0; m < 4; m++) af[m] = *(bf16x8*)&As[wr * 64 + m * 16 + l15][lk * 8];
#pragma unroll
        for (int n = 0; n < 4; n++) bf[n] = *(bf16x8*)&Bs[wc * 64 + n * 16 + l15][lk * 8];
#pragma unroll
        for (int m = 0; m < 4; m++)
#pragma unroll
            for (int n = 0; n < 4; n++)
                acc[m][n] = __builtin_amdgcn_mfma_f32_16x16x32_bf16(af[m], bf[n], acc[m][n], 0, 0, 0);
    }

    __syncthreads();
    if (shalf == 0) {
        const float* tp = T + (size_t)(brow + srow) * RANK;
        *(bf16x8*)&As[srow][0] = pack8(s4(ld4(tp), SCALING), s4(ld4(tp + 4), SCALING));
        *(bf16x8*)&As[srow][8] = pack8(s4(ld4(tp + 8), SCALING), s4(ld4(tp + 12), SCALING));
        const float* bp = lora_B + (size_t)(bcol + srow) * RANK;
        *(bf16x8*)&Bs[srow][0] = pack8(ld4(bp), ld4(bp + 4));
        *(bf16x8*)&Bs[srow][8] = pack8(ld4(bp + 8), ld4(bp + 12));
    } else {
        bf16x8 z;
#pragma unroll
        for (int i = 0; i < 8; i++) z[i] = 0;
        *(bf16x8*)&As[srow][16] = z; *(bf16x8*)&As[srow][24] = z;
        *(bf16x8*)&Bs[srow][16] = z; *(bf16x8*)&Bs[srow][24] = z;
    }
    __syncthreads();
    {
        bf16x8 af[4], bf[4];
#pragma unroll
        for (int m = 0; m < 4; m++) af[m] = *(bf16x8*)&As[wr * 64 + m * 16 + l15][lk * 8];
#pragma unroll
        for (int n = 0; n < 4; n++) bf[n] = *(bf16x8*)&Bs[wc * 64 + n * 16 + l15][lk * 8];
#pragma unroll
        for (int m = 0; m < 4; m++)
#pragma unroll
            for (int n = 0; n < 4; n++)
                acc[m][n] = __builtin_amdgcn_mfma_f32_16x16x32_bf16(af[m], bf[n], acc[m][n], 0, 0, 0);
    }

    const int ocol0 = bcol + wc * 64 + l15;
#pragma unroll
    for (int n = 0; n < 4; n++) {
        const int col = ocol0 + n * 16;
        const float bv = bias[col];
#pragma unroll
        for (int m = 0; m < 4; m++) {
            const int row0 = brow + wr * 64 + m * 16 + lk * 4;
#pragma unroll
            for (int v = 0; v < 4; v++) {
                out[(size_t)(row0 + v) * OUT_F + col] = acc[m][n][v] + bv;
            }
        }
    }
}

extern "C" void kernel_launch(void* const* d_in, const int* in_sizes, int n_in,
                              void* d_out, int out_size, void* d_ws, size_t ws_size,
                              hipStream_t stream) {
    const float* x      = (const float*)d_in[0];
    const float* w      = (const float*)d_in[1];
    const float* bias   = (const float*)d_in[2];
    const float* lora_A = (const float*)d_in[3];
    const float* lora_B = (const float*)d_in[4];
    float* out = (float*)d_out;

    const size_t OFF_T = 0;
    const size_t OFF_W = 655360;
    const size_t OFF_X = 34209792;
    const size_t WS_NEED = 101318656;

    if (ws_size >= WS_NEED) {
        char* ws = (char*)d_ws;
        float*    T   = (float*)(ws + OFF_T);
        ushort_t* wbp = (ushort_t*)(ws + OFF_W);
        ushort_t* xbp = (ushort_t*)(ws + OFF_X);

        prep_kernel<<<1536, 256, 0, stream>>>(x, w, lora_A, xbp, wbp, T);
        gemm8p<<<(M_ROWS / BM) * (OUT_F / BN), 512, 0, stream>>>(xbp, wbp, bias, lora_B, T, out);
    } else {
        float* T = (float*)d_ws;
        lora_t_kernel<<<M_ROWS / 16, 256, 0, stream>>>(x, lora_A, T);
        dim3 grid(OUT_F / 128, M_ROWS / 128);
        lora_gemm_kernel<<<grid, 256, 0, stream>>>(x, w, bias, lora_B, T, out);
    }
}

// Round 10
// 293.572 us; speedup vs baseline: 1.0420x; 1.0420x over previous
//
#include <hip/hip_runtime.h>
#include <hip/hip_bf16.h>

#define IN_F   4096
#define OUT_F  4096
#define M_ROWS 8192
#define RANK   16
#define SCALING 2.0f

#define BM 256
#define BN 256
#define BK 64
#define NT (IN_F / BK)   // 64 K-tiles

typedef __attribute__((ext_vector_type(8))) short bf16x8;
typedef __attribute__((ext_vector_type(4))) float f32x4;
typedef unsigned short ushort_t;

template<int V> struct ic { static constexpr int value = V; };

__device__ __forceinline__ short f2b(float f) {
    union { float f; unsigned u; } c; c.f = f;
    unsigned r = (c.u + 0x7FFFu + ((c.u >> 16) & 1u)) >> 16;
    return (short)r;
}

__device__ __forceinline__ float4 ld4(const float* p) { return *(const float4*)p; }

__device__ __forceinline__ float4 s4(float4 v, float s) {
    v.x *= s; v.y *= s; v.z *= s; v.w *= s; return v;
}

__device__ __forceinline__ bf16x8 pack8(float4 a, float4 b) {
    bf16x8 r;
    r[0] = f2b(a.x); r[1] = f2b(a.y); r[2] = f2b(a.z); r[3] = f2b(a.w);
    r[4] = f2b(b.x); r[5] = f2b(b.y); r[6] = f2b(b.z); r[7] = f2b(b.w);
    return r;
}

__device__ __forceinline__ void gload16(const void* g, void* l) {
    __builtin_amdgcn_global_load_lds(
        (const __attribute__((address_space(1))) unsigned int*)g,
        (__attribute__((address_space(3))) unsigned int*)l, 16, 0, 0);
}

#define FENCE() asm volatile("" ::: "memory")

// ======== prep: convert x,W to bf16 + compute T = x@A^T, one dispatch (r8-proven) ========
__global__ __launch_bounds__(256) void prep_kernel(
        const float* __restrict__ x, const float* __restrict__ w,
        const float* __restrict__ lora_A,
        ushort_t* __restrict__ xb, ushort_t* __restrict__ wb,
        float* __restrict__ T) {
    const int tid = threadIdx.x;
    if (blockIdx.x < 512) {
        __shared__ float part[4][16][16];
        const int lane = tid & 63, wv = tid >> 6;   // 4 waves; wave = K-quarter
        const int l15 = lane & 15, lk = lane >> 4;
        const int r0 = blockIdx.x * 16;
        const int kq = wv * 1024;
        const float*  xr = x      + (size_t)(r0 + l15) * IN_F + kq + lk * 8;
        const float*  ar = lora_A + (size_t)l15        * IN_F + kq + lk * 8;
        ushort_t*     xw = xb     + (size_t)(r0 + l15) * IN_F + kq + lk * 8;
        f32x4 accT = (f32x4){0.f, 0.f, 0.f, 0.f};
#pragma unroll 4
        for (int it = 0; it < 1024; it += 32) {
            bf16x8 xf = pack8(ld4(xr + it), ld4(xr + it + 4));
            *(bf16x8*)(xw + it) = xf;
            bf16x8 afr = pack8(ld4(ar + it), ld4(ar + it + 4));
            accT = __builtin_amdgcn_mfma_f32_16x16x32_bf16(xf, afr, accT, 0, 0, 0);
        }
#pragma unroll
        for (int v = 0; v < 4; v++) part[wv][lk * 4 + v][l15] = accT[v];
        __syncthreads();
        if (tid < 64) {
#pragma unroll
            for (int e = 0; e < 4; e++) {
                const int idx = tid * 4 + e;
                const int i = idx >> 4, j = idx & 15;
                T[(size_t)(r0 + i) * RANK + j] =
                    part[0][i][j] + part[1][i][j] + part[2][i][j] + part[3][i][j];
            }
        }
    } else {
        const int n8w = OUT_F * IN_F / 8;
        int i = (blockIdx.x - 512) * 256 + tid;
        const int stride = 1024 * 256;
        for (; i < n8w; i += stride) {
            const float* p = w + (size_t)i * 8;
            *(bf16x8*)(wb + (size_t)i * 8) = pack8(ld4(p), ld4(p + 4));
        }
    }
}

// ====== main GEMM: 256x256, BK=64, 8-wave, 2-phase/K-tile (32-MFMA clusters), vmcnt(6) ======
__global__ __launch_bounds__(512, 1) void gemm8p(
        const ushort_t* __restrict__ xb, const ushort_t* __restrict__ wb,
        const float* __restrict__ bias, const float* __restrict__ lora_B,
        const float* __restrict__ T, float* __restrict__ out) {

    __shared__ __align__(16) ushort_t As[2][BM * BK];   // 64 KiB
    __shared__ __align__(16) ushort_t Bs[2][BN * BK];   // 64 KiB

    const int tid  = threadIdx.x;
    const int lane = tid & 63, wv = tid >> 6;
    const int wm = wv >> 2, wn = wv & 3;          // 2 x 4 wave grid; wave tile 128x64
    const int l15 = lane & 15, lk = lane >> 4;

    // XCD-aware block swizzle (row-band: each XCD gets 4 by-panels x all bx)
    const int bid = blockIdx.x;
    const int swz = (bid & 7) * 64 + (bid >> 3);
    const int by = swz >> 4, bx = swz & 15;       // 32 x 16 tile grid
    const int brow = by * BM, bcol = bx * BN;

    // ---- staging coords ----
    const int off0 = wv * 2048 + lane * 16;
    const int off1 = off0 + 1024;
    const int row0 = off0 >> 7, row1 = off1 >> 7;
    const int sc0 = ((off0 & 127) ^ ((row0 & 7) << 4)) >> 1;  // pre-swizzled src elem col
    const int sc1 = ((off1 & 127) ^ ((row1 & 7) << 4)) >> 1;
    const int ldst = wv * 1024;

    const size_t gA0 = (size_t)(brow + row0) * IN_F + sc0;
    const size_t gA1 = (size_t)(brow + row1) * IN_F + sc1;
    const size_t gB0 = (size_t)(bcol + row0) * IN_F + sc0;
    const size_t gB1 = (size_t)(bcol + row1) * IN_F + sc1;

    auto SA = [&](int h, int kt, auto BB) {
        constexpr int b = decltype(BB)::value;
        const size_t ho = (size_t)h * (128 * IN_F);
        gload16(xb + gA0 + ho + kt * 64, &As[b][h * 8192 + ldst]);
        gload16(xb + gA1 + ho + kt * 64, &As[b][h * 8192 + ldst + 512]);
    };
    auto SB = [&](int h, int kt, auto BB) {
        constexpr int b = decltype(BB)::value;
        const size_t ho = (size_t)h * (128 * IN_F);
        gload16(wb + gB0 + ho + kt * 64, &Bs[b][h * 8192 + ldst]);
        gload16(wb + gB1 + ho + kt * 64, &Bs[b][h * 8192 + ldst + 512]);
    };

    const int cb0 = (lk * 16) ^ ((l15 & 7) << 4);
    const int cb1 = (64 + lk * 16) ^ ((l15 & 7) << 4);
    const int am = wm * 128, bn = wn * 64;

    f32x4 acc[8][4];
#pragma unroll
    for (int m = 0; m < 8; m++)
#pragma unroll
        for (int n = 0; n < 4; n++) acc[m][n] = (f32x4){0.f, 0.f, 0.f, 0.f};

    bf16x8 af[8], bfq[8];

    // ---- prologue: tile0 full (buf0, 8 loads) + tile1 B0,B1,A0 (buf1, 6 loads) ----
    // A1(tile1) staged at tile-0 phase A. Gate: 14 issued, need first 8 -> vmcnt(6).
    SA(0, 0, ic<0>{}); SA(1, 0, ic<0>{});
    SB(0, 0, ic<0>{}); SB(1, 0, ic<0>{});
    SB(0, 1, ic<1>{}); SB(1, 1, ic<1>{}); SA(0, 1, ic<1>{});
    asm volatile("s_waitcnt vmcnt(6)" ::: "memory");
    __builtin_amdgcn_s_barrier();
    FENCE();

    // 2-phase/K-tile, 2 barriers/K-tile, depth-3 in-flight (vmcnt(6)).
    // phase A: read af-h0(8)+ALL bfq(8); stage A1(t+1)->n; MFMA mh0 x n0123 (32)
    // phase B: read af-h1(8, reg reuse);  stage B0,B1,A0(t+2)->c; MFMA mh1 x n0123 (32); gate vmcnt(6)
    // Race-safety: cur-B0/B1/A0 read only in phase A -> phase-A-end barrier guards phB's
    // stages into c; n-A1's old readers passed the tile-start barrier; af-reg WAR crosses
    // the phase-A-end barrier. Tail clamps re-stage identical/dead data. NT even.
    auto TB = [&](auto CC, int tt) {
        constexpr int c = decltype(CC)::value;
        constexpr int n = c ^ 1;
        const int kt1 = (tt + 1 < NT) ? tt + 1 : NT - 1;
        const int kt2 = (tt + 2 < NT) ? tt + 2 : NT - 1;

        // ---- phase A ----
#pragma unroll
        for (int mi = 0; mi < 4; mi++) {
            const char* rp = (const char*)&As[c][0] + (am + mi * 16 + l15) * 128;
            af[mi * 2]     = *(const bf16x8*)(rp + cb0);
            af[mi * 2 + 1] = *(const bf16x8*)(rp + cb1);
        }
#pragma unroll
        for (int ni = 0; ni < 4; ni++) {
            const char* rp = (const char*)&Bs[c][0] + (bn + ni * 16 + l15) * 128;
            bfq[ni * 2]     = *(const bf16x8*)(rp + cb0);
            bfq[ni * 2 + 1] = *(const bf16x8*)(rp + cb1);
        }
        SA(1, kt1, ic<n>{});
        __builtin_amdgcn_s_setprio(1);
#pragma unroll
        for (int mi = 0; mi < 4; mi++)
#pragma unroll
            for (int ni = 0; ni < 4; ni++)
#pragma unroll
                for (int ks = 0; ks < 2; ks++)
                    acc[mi][ni] = __builtin_amdgcn_mfma_f32_16x16x32_bf16(
                        af[mi * 2 + ks], bfq[ni * 2 + ks], acc[mi][ni], 0, 0, 0);
        __builtin_amdgcn_s_setprio(0);
        FENCE();
        __builtin_amdgcn_s_barrier();
        FENCE();

        // ---- phase B ----
#pragma unroll
        for (int mi = 0; mi < 4; mi++) {
            const char* rp = (const char*)&As[c][0] + (am + 64 + mi * 16 + l15) * 128;
            af[mi * 2]     = *(const bf16x8*)(rp + cb0);
            af[mi * 2 + 1] = *(const bf16x8*)(rp + cb1);
        }
        SB(0, kt2, ic<c>{});
        SB(1, kt2, ic<c>{});
        SA(0, kt2, ic<c>{});
        __builtin_amdgcn_s_setprio(1);
#pragma unroll
        for (int mi = 0; mi < 4; mi++)
#pragma unroll
            for (int ni = 0; ni < 4; ni++)
#pragma unroll
                for (int ks = 0; ks < 2; ks++)
                    acc[4 + mi][ni] = __builtin_amdgcn_mfma_f32_16x16x32_bf16(
                        af[mi * 2 + ks], bfq[ni * 2 + ks], acc[4 + mi][ni], 0, 0, 0);
        __builtin_amdgcn_s_setprio(0);
        asm volatile("s_waitcnt vmcnt(6)" ::: "memory");  // tile t+1 fully landed
        __builtin_amdgcn_s_barrier();
        FENCE();
    };

    for (int tt = 0; tt < NT; tt += 2) {
        TB(ic<0>{}, tt);
        TB(ic<1>{}, tt + 1);
    }

    // ---- LoRA rank-update: one K=32 MFMA step (linear LDS, reg-staged) ----
    asm volatile("s_waitcnt vmcnt(0)" ::: "memory");
    __builtin_amdgcn_s_barrier();
    {
        const int r = tid >> 1, hh = tid & 1;
        ushort_t* LA = &As[0][0];
        ushort_t* LB = &Bs[0][0];
        if (hh == 0) {
            const float* tp = T + (size_t)(brow + r) * RANK;
            *(bf16x8*)&LA[r * 32]     = pack8(s4(ld4(tp), SCALING), s4(ld4(tp + 4), SCALING));
            *(bf16x8*)&LA[r * 32 + 8] = pack8(s4(ld4(tp + 8), SCALING), s4(ld4(tp + 12), SCALING));
            const float* bp = lora_B + (size_t)(bcol + r) * RANK;
            *(bf16x8*)&LB[r * 32]     = pack8(ld4(bp), ld4(bp + 4));
            *(bf16x8*)&LB[r * 32 + 8] = pack8(ld4(bp + 8), ld4(bp + 12));
        } else {
            bf16x8 z;
#pragma unroll
            for (int i = 0; i < 8; i++) z[i] = 0;
            *(bf16x8*)&LA[r * 32 + 16] = z; *(bf16x8*)&LA[r * 32 + 24] = z;
            *(bf16x8*)&LB[r * 32 + 16] = z; *(bf16x8*)&LB[r * 32 + 24] = z;
        }
    }
    __syncthreads();
    {
        const ushort_t* LA = &As[0][0];
        const ushort_t* LB = &Bs[0][0];
        bf16x8 bfL[4];
#pragma unroll
        for (int n = 0; n < 4; n++)
            bfL[n] = *(const bf16x8*)&LB[(bn + n * 16 + l15) * 32 + lk * 8];
#pragma unroll
        for (int m = 0; m < 8; m++) {
            bf16x8 afL = *(const bf16x8*)&LA[(am + m * 16 + l15) * 32 + lk * 8];
#pragma unroll
            for (int n = 0; n < 4; n++)
                acc[m][n] = __builtin_amdgcn_mfma_f32_16x16x32_bf16(afL, bfL[n], acc[m][n], 0, 0, 0);
        }
    }

    // ---- epilogue: + bias, store ----
#pragma unroll
    for (int n = 0; n < 4; n++) {
        const int col = bcol + bn + n * 16 + l15;
        const float bv = bias[col];
#pragma unroll
        for (int m = 0; m < 8; m++) {
            const int row0_ = brow + am + m * 16 + lk * 4;
#pragma unroll
            for (int v = 0; v < 4; v++)
                out[(size_t)(row0_ + v) * OUT_F + col] = acc[m][n][v] + bv;
        }
    }
}

// ================= fp32 fallback path (small ws) =================
__global__ __launch_bounds__(256) void lora_t_kernel(const float* __restrict__ x,
                                                     const float* __restrict__ lora_A,
                                                     float* __restrict__ T) {
    const int t   = threadIdx.x;
    const int row = blockIdx.x * 16 + (t >> 4);
    const int rr  = t & 15;
    const float* xr = x + (size_t)row * IN_F;
    const float* ar = lora_A + (size_t)rr * IN_F;
    float acc = 0.f;
#pragma unroll 8
    for (int k = 0; k < IN_F; k += 4) {
        float4 xv = ld4(xr + k);
        float4 av = ld4(ar + k);
        acc += xv.x * av.x + xv.y * av.y + xv.z * av.z + xv.w * av.w;
    }
    T[row * RANK + rr] = acc;
}

__global__ __launch_bounds__(256) void lora_gemm_kernel(
        const float* __restrict__ x, const float* __restrict__ w,
        const float* __restrict__ bias, const float* __restrict__ lora_B,
        const float* __restrict__ T, float* __restrict__ out) {

    __shared__ __align__(16) short As[128][32];
    __shared__ __align__(16) short Bs[128][32];

    const int t    = threadIdx.x;
    const int brow = blockIdx.y * 128;
    const int bcol = blockIdx.x * 128;
    const int srow  = t >> 1;
    const int shalf = (t & 1) << 4;
    const float* xa = x + (size_t)(brow + srow) * IN_F + shalf;
    const float* wb = w + (size_t)(bcol + srow) * IN_F + shalf;
    const int lane = t & 63;
    const int wv   = t >> 6;
    const int wr   = wv >> 1, wc = wv & 1;
    const int l15  = lane & 15, lk = lane >> 4;

    f32x4 acc[4][4];
#pragma unroll
    for (int m = 0; m < 4; m++)
#pragma unroll
        for (int n = 0; n < 4; n++)
            acc[m][n] = (f32x4){0.f, 0.f, 0.f, 0.f};

    for (int k0 = 0; k0 < IN_F; k0 += 32) {
        float4 a0 = ld4(xa + k0);      float4 a1 = ld4(xa + k0 + 4);
        float4 a2 = ld4(xa + k0 + 8);  float4 a3 = ld4(xa + k0 + 12);
        float4 b0 = ld4(wb + k0);      float4 b1 = ld4(wb + k0 + 4);
        float4 b2 = ld4(wb + k0 + 8);  float4 b3 = ld4(wb + k0 + 12);

        __syncthreads();
        *(bf16x8*)&As[srow][shalf]     = pack8(a0, a1);
        *(bf16x8*)&As[srow][shalf + 8] = pack8(a2, a3);
        *(bf16x8*)&Bs[srow][shalf]     = pack8(b0, b1);
        *(bf16x8*)&Bs[srow][shalf + 8] = pack8(b2, b3);
        __syncthreads();

        bf16x8 af[4], bf[4];
#pragma unroll
        for (int m = 0; m < 4; m++) af[m] = *(bf16x8*)&As[wr * 64 + m * 16 + l15][lk * 8];
#pragma unroll
        for (int n = 0; n < 4; n++) bf[n] = *(bf16x8*)&Bs[wc * 64 + n * 16 + l15][lk * 8];
#pragma unroll
        for (int m = 0; m < 4; m++)
#pragma unroll
            for (int n = 0; n < 4; n++)
                acc[m][n] = __builtin_amdgcn_mfma_f32_16x16x32_bf16(af[m], bf[n], acc[m][n], 0, 0, 0);
    }

    __syncthreads();
    if (shalf == 0) {
        const float* tp = T + (size_t)(brow + srow) * RANK;
        *(bf16x8*)&As[srow][0] = pack8(s4(ld4(tp), SCALING), s4(ld4(tp + 4), SCALING));
        *(bf16x8*)&As[srow][8] = pack8(s4(ld4(tp + 8), SCALING), s4(ld4(tp + 12), SCALING));
        const float* bp = lora_B + (size_t)(bcol + srow) * RANK;
        *(bf16x8*)&Bs[srow][0] = pack8(ld4(bp), ld4(bp + 4));
        *(bf16x8*)&Bs[srow][8] = pack8(ld4(bp + 8), ld4(bp + 12));
    } else {
        bf16x8 z;
#pragma unroll
        for (int i = 0; i < 8; i++) z[i] = 0;
        *(bf16x8*)&As[srow][16] = z; *(bf16x8*)&As[srow][24] = z;
        *(bf16x8*)&Bs[srow][16] = z; *(bf16x8*)&Bs[srow][24] = z;
    }
    __syncthreads();
    {
        bf16x8 af[4], bf[4];
#pragma unroll
        for (int m = 0; m < 4; m++) af[m] = *(bf16x8*)&As[wr * 64 + m * 16 + l15][lk * 8];
#pragma unroll
        for (int n = 0; n < 4; n++) bf[n] = *(bf16x8*)&Bs[wc * 64 + n * 16 + l15][lk * 8];
#pragma unroll
        for (int m = 0; m < 4; m++)
#pragma unroll
            for (int n = 0; n < 4; n++)
                acc[m][n] = __builtin_amdgcn_mfma_f32_16x16x32_bf16(af[m], bf[n], acc[m][n], 0, 0, 0);
    }

    const int ocol0 = bcol + wc * 64 + l15;
#pragma unroll
    for (int n = 0; n < 4; n++) {
        const int col = ocol0 + n * 16;
        const float bv = bias[col];
#pragma unroll
        for (int m = 0; m < 4; m++) {
            const int row0 = brow + wr * 64 + m * 16 + lk * 4;
#pragma unroll
            for (int v = 0; v < 4; v++) {
                out[(size_t)(row0 + v) * OUT_F + col] = acc[m][n][v] + bv;
            }
        }
    }
}

extern "C" void kernel_launch(void* const* d_in, const int* in_sizes, int n_in,
                              void* d_out, int out_size, void* d_ws, size_t ws_size,
                              hipStream_t stream) {
    const float* x      = (const float*)d_in[0];
    const float* w      = (const float*)d_in[1];
    const float* bias   = (const float*)d_in[2];
    const float* lora_A = (const float*)d_in[3];
    const float* lora_B = (const float*)d_in[4];
    float* out = (float*)d_out;

    const size_t OFF_T = 0;
    const size_t OFF_W = 655360;
    const size_t OFF_X = 34209792;
    const size_t WS_NEED = 101318656;

    if (ws_size >= WS_NEED) {
        char* ws = (char*)d_ws;
        float*    T   = (float*)(ws + OFF_T);
        ushort_t* wbp = (ushort_t*)(ws + OFF_W);
        ushort_t* xbp = (ushort_t*)(ws + OFF_X);

        prep_kernel<<<1536, 256, 0, stream>>>(x, w, lora_A, xbp, wbp, T);
        gemm8p<<<(M_ROWS / BM) * (OUT_F / BN), 512, 0, stream>>>(xbp, wbp, bias, lora_B, T, out);
    } else {
        float* T = (float*)d_ws;
        lora_t_kernel<<<M_ROWS / 16, 256, 0, stream>>>(x, lora_A, T);
        dim3 grid(OUT_F / 128, M_ROWS / 128);
        lora_gemm_kernel<<<grid, 256, 0, stream>>>(x, w, bias, lora_B, T, out);
    }
}